// Round 7
// baseline (90.681 us; speedup 1.0000x reference)
//
#include <hip/hip_runtime.h>

typedef _Float16 half2_t __attribute__((ext_vector_type(2)));

// Single fused kernel.
// Stage 1 (per block, redundant across blocks — cheap): fold map_w/map_b into
//   lin_w giving M[p][k][i] = sum_j lin_w[k,p*8+j]*map_w[j*4+i]  (f16 in LDS),
//   and bias partials b'[k] = lin_b[k] + sum_{p,j} lin_w[k,p*8+j]*map_b[j].
//   Patches 192..195 pre-scaled by 1/16 (16-lane-redundant tail trick).
// Stage 2: one wave per image, 4 images per wave; closed-form circuit
//   (verified R3-R6): <Z_w> = cth_w*T1_w - sth_w*T2_w with
//   T1=(C0,C0C1,C0C1C2,C0C1C2C3), T2=(S0S1,S1S2,S2S3,S3),
//   C_i=cos(ang_i+vp0_i), S_i=sin(ang_i+vp0_i); Taylor for the tiny ang.

// ---------- helpers ----------
static __device__ __forceinline__ half2_t pk2(float a, float b) {
#if __has_builtin(__builtin_amdgcn_cvt_pkrtz)
    return __builtin_bit_cast(half2_t, __builtin_amdgcn_cvt_pkrtz(a, b));
#else
    half2_t r; r.x = (_Float16)a; r.y = (_Float16)b; return r;
#endif
}

static __device__ __forceinline__ float fdot2f(half2_t a, half2_t b, float c) {
#if __has_builtin(__builtin_amdgcn_fdot2)
    return __builtin_amdgcn_fdot2(a, b, c, false);
#else
    return c + (float)a.x * (float)b.x + (float)a.y * (float)b.y;
#endif
}

#if __has_builtin(__builtin_amdgcn_update_dpp)
template <int CTRL>
static __device__ __forceinline__ float dpp_add(float x) {
    int t = __builtin_amdgcn_update_dpp(0, __float_as_int(x), CTRL, 0xf, 0xf, false);
    return x + __int_as_float(t);
}
// canonical gfx9 wave64 sum; TOTAL lands in lane 63
static __device__ __forceinline__ float wave_sum(float x) {
    x = dpp_add<0x111>(x);   // row_shr:1
    x = dpp_add<0x112>(x);   // row_shr:2
    x = dpp_add<0x114>(x);   // row_shr:4
    x = dpp_add<0x118>(x);   // row_shr:8
    x = dpp_add<0x142>(x);   // row_bcast:15
    x = dpp_add<0x143>(x);   // row_bcast:31
    return x;
}
#define TOTAL_LANE 63
#else
static __device__ __forceinline__ float wave_sum(float x) {
    #pragma unroll
    for (int off = 32; off; off >>= 1) x += __shfl_xor(x, off, 64);
    return x;
}
#define TOTAL_LANE 63
#endif

__global__ __launch_bounds__(256, 3) void quanv_all(
    const float* __restrict__ x,
    const float* __restrict__ vp,
    const float* __restrict__ map_w,
    const float* __restrict__ map_b,
    const float* __restrict__ lin_w,
    const float* __restrict__ lin_b,
    float* __restrict__ out, int B)
{
    __shared__ half2_t sM[20 * 256];   // [(k*2+h)*256 + p]
    __shared__ float sPart[4][10];     // per-wave bias partials

    const int tid  = threadIdx.x;
    const int lane = tid & 63;
    const int wv   = tid >> 6;

    // ---------------- stage 1: per-block fold ----------------
    float pb[10];
    #pragma unroll
    for (int k = 0; k < 10; ++k) pb[k] = 0.0f;

    {
        const int p = tid;
        if (p < 196) {
            float mw[32], mb[8];
            #pragma unroll
            for (int j = 0; j < 8; ++j) {
                const float4 m4 = *(const float4*)(map_w + j * 4);
                mw[j * 4 + 0] = m4.x; mw[j * 4 + 1] = m4.y;
                mw[j * 4 + 2] = m4.z; mw[j * 4 + 3] = m4.w;
                mb[j] = map_b[j];
            }
            const float sc = (p >= 192) ? 0.0625f : 1.0f;
            #pragma unroll
            for (int k = 0; k < 10; ++k) {
                const float* lw = lin_w + k * 1568 + p * 8;
                const float4 w0 = *(const float4*)lw;
                const float4 w1 = *(const float4*)(lw + 4);
                const float l[8] = {w0.x, w0.y, w0.z, w0.w,
                                    w1.x, w1.y, w1.z, w1.w};
                float m0 = 0.f, m1 = 0.f, m2 = 0.f, m3 = 0.f;
                #pragma unroll
                for (int j = 0; j < 8; ++j) {
                    m0 = fmaf(l[j], mw[j * 4 + 0], m0);
                    m1 = fmaf(l[j], mw[j * 4 + 1], m1);
                    m2 = fmaf(l[j], mw[j * 4 + 2], m2);
                    m3 = fmaf(l[j], mw[j * 4 + 3], m3);
                    pb[k] = fmaf(l[j], mb[j], pb[k]);
                }
                sM[(k * 2 + 0) * 256 + p] = pk2(m0 * sc, m1 * sc);
                sM[(k * 2 + 1) * 256 + p] = pk2(m2 * sc, m3 * sc);
            }
        } else {
            half2_t z; z.x = (_Float16)0.f; z.y = (_Float16)0.f;
            #pragma unroll
            for (int r = 0; r < 20; ++r) sM[r * 256 + p] = z;
        }
    }

    #pragma unroll
    for (int k = 0; k < 10; ++k) pb[k] = wave_sum(pb[k]);
    if (lane == TOTAL_LANE) {
        #pragma unroll
        for (int k = 0; k < 10; ++k) sPart[wv][k] = pb[k];
    }
    __syncthreads();

    // ---------------- stage 2: images ----------------
    // trig params (wave-uniform values, computed per-thread)
    float cva[4], sva[4], cth[4], sth[4];
    #pragma unroll
    for (int i = 0; i < 4; ++i) {
        __sincosf(vp[i],     &sva[i], &cva[i]);
        __sincosf(vp[4 + i], &sth[i], &cth[i]);
    }

    // patch assignment: j<3 -> p=j*64+lane; j=3 -> 192+(lane&3) (redundant)
    int pidx[4];
    #pragma unroll
    for (int j = 0; j < 3; ++j) pidx[j] = j * 64 + lane;
    pidx[3] = 192 + (lane & 3);

    // M fragments LDS -> VGPRs (80 half2); stride-1 per read = conflict-free
    half2_t Mr[10][2][4];
    #pragma unroll
    for (int k = 0; k < 10; ++k)
        #pragma unroll
        for (int h = 0; h < 2; ++h)
            #pragma unroll
            for (int j = 0; j < 4; ++j)
                Mr[k][h][j] = sM[(k * 2 + h) * 256 + pidx[j]];

    int off0[4];
    #pragma unroll
    for (int j = 0; j < 4; ++j) {
        const int p  = pidx[j];
        const int py = p / 14;
        off0[j] = py * 56 + (p - py * 14) * 2;
    }

    const int step = gridDim.x * 4;
    for (int b = blockIdx.x * 4 + wv; b < B; b += step) {
        const float* img = x + (size_t)b * 784;
        float2 q0[4], q1[4];
        #pragma unroll
        for (int j = 0; j < 4; ++j) {
            q0[j] = *(const float2*)(img + off0[j]);
            q1[j] = *(const float2*)(img + off0[j] + 28);
        }

        float lg[10];
        #pragma unroll
        for (int k = 0; k < 10; ++k) lg[k] = 0.0f;

        #pragma unroll
        for (int j = 0; j < 4; ++j) {
            const float t[4] = {q0[j].x, q0[j].y, q1[j].x, q1[j].y};
            float C[4], S[4];
            #pragma unroll
            for (int i = 0; i < 4; ++i) {
                const float a  = t[i] * (1.0f / 255.0f);
                const float a2 = a * a;
                const float ct = fmaf(a2, -0.5f, 1.0f);            // cos a
                const float st = a * fmaf(a2, -1.0f / 6.0f, 1.0f); // sin a
                C[i] = fmaf(cva[i], ct, -sva[i] * st);
                S[i] = fmaf(sva[i], ct,  cva[i] * st);
            }
            const float P1 = C[0] * C[1], P2 = P1 * C[2], P3 = P2 * C[3];
            const float m0 = fmaf(cth[0], C[0], -sth[0] * (S[0] * S[1]));
            const float m1 = fmaf(cth[1], P1,   -sth[1] * (S[1] * S[2]));
            const float m2 = fmaf(cth[2], P2,   -sth[2] * (S[2] * S[3]));
            const float m3 = fmaf(cth[3], P3,   -sth[3] * S[3]);

            const half2_t h01 = pk2(m0, m1);
            const half2_t h23 = pk2(m2, m3);
            #pragma unroll
            for (int k = 0; k < 10; ++k)
                lg[k] = fdot2f(h01, Mr[k][0][j],
                         fdot2f(h23, Mr[k][1][j], lg[k]));
        }

        #pragma unroll
        for (int k = 0; k < 10; ++k) lg[k] = wave_sum(lg[k]);

        if (lane == TOTAL_LANE) {
            float logits[10], mx = -1e30f;
            #pragma unroll
            for (int k = 0; k < 10; ++k) {
                logits[k] = lg[k] + lin_b[k]
                          + sPart[0][k] + sPart[1][k]
                          + sPart[2][k] + sPart[3][k];
                mx = fmaxf(mx, logits[k]);
            }
            float sum = 0.0f;
            #pragma unroll
            for (int k = 0; k < 10; ++k) sum += __expf(logits[k] - mx);
            const float lse = mx + __logf(sum);
            float* o = out + (size_t)b * 10;
            #pragma unroll
            for (int k = 0; k < 10; k += 2)
                *(float2*)(o + k) = make_float2(logits[k] - lse,
                                                logits[k + 1] - lse);
        }
    }
}

extern "C" void kernel_launch(void* const* d_in, const int* in_sizes, int n_in,
                              void* d_out, int out_size, void* d_ws, size_t ws_size,
                              hipStream_t stream) {
    const float* x     = (const float*)d_in[0];
    const float* vp    = (const float*)d_in[1];
    const float* map_w = (const float*)d_in[2];
    const float* map_b = (const float*)d_in[3];
    const float* lin_w = (const float*)d_in[4];
    const float* lin_b = (const float*)d_in[5];
    float* out = (float*)d_out;

    const int B = in_sizes[0] / 784;          // 8192
    const int grid = (B + 15) / 16;           // 4 waves/block x 4 images/wave

    quanv_all<<<grid, 256, 0, stream>>>(x, vp, map_w, map_b, lin_w, lin_b, out, B);
}

// Round 8
// 85.948 us; speedup vs baseline: 1.0551x; 1.0551x over previous
//
#include <hip/hip_runtime.h>

typedef _Float16 half2_t __attribute__((ext_vector_type(2)));

// ws float layout:
//   [0..3]  cva = cos(vp[0][i])     [4..7]   sva = sin(vp[0][i])
//   [8..11] cth = cos(vp[1][w])     [12..15] sth = sin(vp[1][w])
//   [16..25] folded bias b'[k] = lin_b[k] + sum_{p,j} lin_w[k,p*8+j]*map_b[j]
//   float offset 32: half2 M[(k*2+h)*256 + p], p in [0,196);
//     M[p][k][i] = sum_j lin_w[k,p*8+j]*map_w[j*4+i], f16;
//     p in [192,196) pre-scaled by 1/16 (16-lane-redundant tail trick).

#define WS_MOFF 32
#define NWAVES  4096   // grid 1024 blocks x 4 waves; 2 images per wave

// ---------- helpers ----------
static __device__ __forceinline__ half2_t pk2(float a, float b) {
#if __has_builtin(__builtin_amdgcn_cvt_pkrtz)
    return __builtin_bit_cast(half2_t, __builtin_amdgcn_cvt_pkrtz(a, b));
#else
    half2_t r; r.x = (_Float16)a; r.y = (_Float16)b; return r;
#endif
}

static __device__ __forceinline__ float fdot2f(half2_t a, half2_t b, float c) {
#if __has_builtin(__builtin_amdgcn_fdot2)
    return __builtin_amdgcn_fdot2(a, b, c, false);
#else
    return c + (float)a.x * (float)b.x + (float)a.y * (float)b.y;
#endif
}

#if __has_builtin(__builtin_amdgcn_update_dpp)
template <int CTRL>
static __device__ __forceinline__ float dpp_add(float x) {
    int t = __builtin_amdgcn_update_dpp(0, __float_as_int(x), CTRL, 0xf, 0xf, false);
    return x + __int_as_float(t);
}
// canonical gfx9 wave64 sum; TOTAL lands in lane 63
static __device__ __forceinline__ float wave_sum(float x) {
    x = dpp_add<0x111>(x);   // row_shr:1
    x = dpp_add<0x112>(x);   // row_shr:2
    x = dpp_add<0x114>(x);   // row_shr:4
    x = dpp_add<0x118>(x);   // row_shr:8
    x = dpp_add<0x142>(x);   // row_bcast:15
    x = dpp_add<0x143>(x);   // row_bcast:31
    return x;
}
#else
static __device__ __forceinline__ float wave_sum(float x) {
    #pragma unroll
    for (int off = 32; off; off >>= 1) x += __shfl_xor(x, off, 64);
    return x;
}
#endif

// ---------- precompute: fold map_w/map_b into lin_w, f16-pack M ----------
__global__ __launch_bounds__(256) void quanv_pre(
    const float* __restrict__ vp,
    const float* __restrict__ map_w,
    const float* __restrict__ map_b,
    const float* __restrict__ lin_w,
    const float* __restrict__ lin_b,
    float* __restrict__ ws)
{
    const int k = blockIdx.x;    // 0..9
    const int p = threadIdx.x;   // 0..255
    __shared__ float s_part[4];

    half2_t* Mws = (half2_t*)(ws + WS_MOFF);

    float pb = 0.0f;
    if (p < 196) {
        const float* lw = lin_w + k * 1568 + p * 8;
        const float4 w0 = *(const float4*)lw;
        const float4 w1 = *(const float4*)(lw + 4);
        const float l[8] = {w0.x, w0.y, w0.z, w0.w, w1.x, w1.y, w1.z, w1.w};
        float m[4] = {0.f, 0.f, 0.f, 0.f};
        #pragma unroll
        for (int j = 0; j < 8; ++j) {
            #pragma unroll
            for (int i = 0; i < 4; ++i)
                m[i] = fmaf(l[j], map_w[j * 4 + i], m[i]);
            pb = fmaf(l[j], map_b[j], pb);
        }
        const float sc = (p >= 192) ? 0.0625f : 1.0f;  // 16-lane-redundant tail
        Mws[(k * 2 + 0) * 256 + p] = pk2(m[0] * sc, m[1] * sc);
        Mws[(k * 2 + 1) * 256 + p] = pk2(m[2] * sc, m[3] * sc);
    }

    #pragma unroll
    for (int off = 32; off; off >>= 1) pb += __shfl_xor(pb, off, 64);
    if ((p & 63) == 0) s_part[p >> 6] = pb;
    __syncthreads();
    if (p == 0)
        ws[16 + k] = lin_b[k] + s_part[0] + s_part[1] + s_part[2] + s_part[3];
    if (k == 0 && p < 4) {
        ws[p]      = cosf(vp[p]);
        ws[4 + p]  = sinf(vp[p]);
        ws[8 + p]  = cosf(vp[4 + p]);
        ws[12 + p] = sinf(vp[4 + p]);
    }
}

// ---------- main: one wave per image-stream (2 images/wave), M in f16 VGPRs
__global__ __launch_bounds__(256, 3) void quanv_main(
    const float* __restrict__ x,
    const float* __restrict__ ws,
    float* __restrict__ out, int B)
{
    const int lane = threadIdx.x & 63;
    const int wave = blockIdx.x * 4 + (threadIdx.x >> 6);
    if (wave >= B) return;

    // wave-uniform params (scalar loads) + derived trig constants
    float cva[4], sva[4], cth[4], sth[4], nsv[4], mhc[4], mhs[4];
    #pragma unroll
    for (int i = 0; i < 4; ++i) {
        cva[i] = ws[i];     sva[i] = ws[4 + i];
        cth[i] = ws[8 + i]; sth[i] = ws[12 + i];
        nsv[i] = -sva[i];
        mhc[i] = -0.5f * cva[i];
        mhs[i] = -0.5f * sva[i];
    }

    // patch assignment: j<3 -> p=j*64+lane; j=3 -> 192+(lane&3) (redundant)
    int pidx[4];
    #pragma unroll
    for (int j = 0; j < 3; ++j) pidx[j] = j * 64 + lane;
    pidx[3] = 192 + (lane & 3);

    // preload M fragments into VGPRs (80 half2 = 80 VGPRs), coalesced
    const half2_t* Mws = (const half2_t*)(ws + WS_MOFF);
    half2_t Mr[10][2][4];
    #pragma unroll
    for (int k = 0; k < 10; ++k)
        #pragma unroll
        for (int h = 0; h < 2; ++h)
            #pragma unroll
            for (int j = 0; j < 4; ++j)
                Mr[k][h][j] = Mws[(k * 2 + h) * 256 + pidx[j]];

    // fixed per-lane pixel offsets
    int off0[4];
    #pragma unroll
    for (int j = 0; j < 4; ++j) {
        const int p  = pidx[j];
        const int py = p / 14;
        off0[j] = py * 56 + (p - py * 14) * 2;
    }

    // software-pipelined pixel loads
    float2 nq0[4], nq1[4];
    {
        const float* img = x + (size_t)wave * 784;
        #pragma unroll
        for (int j = 0; j < 4; ++j) {
            nq0[j] = *(const float2*)(img + off0[j]);
            nq1[j] = *(const float2*)(img + off0[j] + 28);
        }
    }

    for (int b = wave; b < B; b += NWAVES) {
        float2 q0[4], q1[4];
        #pragma unroll
        for (int j = 0; j < 4; ++j) { q0[j] = nq0[j]; q1[j] = nq1[j]; }

        int bn = b + NWAVES;
        bn = bn < B ? bn : b;
        {
            const float* img = x + (size_t)bn * 784;
            #pragma unroll
            for (int j = 0; j < 4; ++j) {
                nq0[j] = *(const float2*)(img + off0[j]);
                nq1[j] = *(const float2*)(img + off0[j] + 28);
            }
        }

        float lg[10];
        #pragma unroll
        for (int k = 0; k < 10; ++k) lg[k] = 0.0f;

        #pragma unroll
        for (int j = 0; j < 4; ++j) {
            const float t[4] = {q0[j].x, q0[j].y, q1[j].x, q1[j].y};
            float C[4], S[4];
            #pragma unroll
            for (int i = 0; i < 4; ++i) {
                // C=cos(v+a), S=sin(v+a), a=t/255<0.004:
                //   C = c - a*s - (a^2/2)*c ; S = s + a*c - (a^2/2)*s
                const float a  = t[i] * (1.0f / 255.0f);
                const float a2 = a * a;
                C[i] = fmaf(a2, mhc[i], fmaf(a, nsv[i], cva[i]));
                S[i] = fmaf(a2, mhs[i], fmaf(a, cva[i], sva[i]));
            }
            const float P1 = C[0] * C[1], P2 = P1 * C[2], P3 = P2 * C[3];
            const float m0 = fmaf(cth[0], C[0], -sth[0] * (S[0] * S[1]));
            const float m1 = fmaf(cth[1], P1,   -sth[1] * (S[1] * S[2]));
            const float m2 = fmaf(cth[2], P2,   -sth[2] * (S[2] * S[3]));
            const float m3 = fmaf(cth[3], P3,   -sth[3] * S[3]);

            const half2_t h01 = pk2(m0, m1);
            const half2_t h23 = pk2(m2, m3);
            #pragma unroll
            for (int k = 0; k < 10; ++k)
                lg[k] = fdot2f(h01, Mr[k][0][j],
                         fdot2f(h23, Mr[k][1][j], lg[k]));
        }

        // DPP wave reduction: totals land in lane 63
        #pragma unroll
        for (int k = 0; k < 10; ++k) lg[k] = wave_sum(lg[k]);

        if (lane == 63) {
            float logits[10], mx = -1e30f;
            #pragma unroll
            for (int k = 0; k < 10; ++k) {
                logits[k] = lg[k] + ws[16 + k];
                mx = fmaxf(mx, logits[k]);
            }
            float sum = 0.0f;
            #pragma unroll
            for (int k = 0; k < 10; ++k) sum += __expf(logits[k] - mx);
            const float lse = mx + __logf(sum);
            float* o = out + (size_t)b * 10;
            #pragma unroll
            for (int k = 0; k < 10; k += 2)
                *(float2*)(o + k) = make_float2(logits[k] - lse,
                                                logits[k + 1] - lse);
        }
    }
}

extern "C" void kernel_launch(void* const* d_in, const int* in_sizes, int n_in,
                              void* d_out, int out_size, void* d_ws, size_t ws_size,
                              hipStream_t stream) {
    const float* x     = (const float*)d_in[0];
    const float* vp    = (const float*)d_in[1];
    const float* map_w = (const float*)d_in[2];
    const float* map_b = (const float*)d_in[3];
    const float* lin_w = (const float*)d_in[4];
    const float* lin_b = (const float*)d_in[5];
    float* out = (float*)d_out;
    float* ws  = (float*)d_ws;

    const int B = in_sizes[0] / 784;

    quanv_pre<<<10, 256, 0, stream>>>(vp, map_w, map_b, lin_w, lin_b, ws);
    quanv_main<<<NWAVES / 4, 256, 0, stream>>>(x, ws, out, B);
}